// Round 13
// baseline (287.204 us; speedup 1.0000x reference)
//
#include <hip/hip_runtime.h>
#include <hip/hip_bf16.h>

#define N_NODES 100000
#define N_EDGES 1600000
#define DIM 64

#define K1 ((N_NODES + 255) / 256)               // 391 buckets of 256 nodes
#define PACKB4 ((N_NODES * DIM / 4 + 255) / 256) // 6250 (exact: N*DIM = 6.4M)
#define PTILE 8192
#define PARTB ((N_EDGES + PTILE - 1) / PTILE)    // 196 partition-role blocks
#define CAP 4480                                 // bucket slot: mean 4096 + 6 sigma
#define QCAP 1344                                // quarter-bucket: mean 1024 + 10 sigma

typedef __attribute__((ext_vector_type(8))) short bf16x8;
typedef __attribute__((ext_vector_type(4))) float f32x4;

#if defined(__has_builtin)
#if __has_builtin(__builtin_amdgcn_fdot2_f32_bf16)
#define HAVE_DOT2 1
typedef __attribute__((ext_vector_type(2))) __bf16 bf16x2v;
#endif
#endif

// ---------------- ws layout ----------------
// At      : 32 KB bf16 (combined epilogue matrix, transposed)
// cvec    : 1 KB
// records : K1 * CAP * 8 B fixed bucket slots (u64 {hi=bf16x2 coef,
//           lo=src | dst_local<<17}); bucket b owns [b*CAP, b*CAP+cursor[b]).
//           Within-bucket order ARBITRARY — pull re-sorts in LDS.
// hpack   : N*DIM*4B ({bf16 hr, bf16 hi} interleaved)
// cursor  : K1 ints (memset 0; bumped by partition reservation; final = count)
// total ~39.7 MB

__device__ __forceinline__ unsigned pack_bf16x2(float lo, float hi) {
  unsigned ulo = (unsigned)__hip_bfloat16_raw(__float2bfloat16(lo)).x;
  unsigned uhi = (unsigned)__hip_bfloat16_raw(__float2bfloat16(hi)).x;
  return ulo | (uhi << 16);
}
__device__ __forceinline__ float unpack_lo(unsigned u) {
  return __int_as_float((int)(u << 16));
}
__device__ __forceinline__ float unpack_hi(unsigned u) {
  return __int_as_float((int)(u & 0xFFFF0000u));
}
__device__ __forceinline__ unsigned short f2bf(float x) {
  return __hip_bfloat16_raw(__float2bfloat16(x)).x;
}

// MEGA kernel (r13): pack ∥ At ∥ partition fused — all roles independent
// (partition never reads hpack/At; fixed bucket slots need no prefix scan).
// Roles: [0,PACKB4) pack_h; [PACKB4,+64) At/cvec (LDS-staged W, r12-verified);
// [PACKB4+64, +PARTB) partition by chunk-reservation into fixed slots.
__global__ __launch_bounds__(256) void mega_kernel(
    const float* __restrict__ h_real, const float* __restrict__ h_imag,
    unsigned* __restrict__ hpack, const float* __restrict__ W1,
    const float* __restrict__ b1, const float* __restrict__ W2,
    const float* __restrict__ b2, unsigned short* __restrict__ At,
    float* __restrict__ cvec, const int* __restrict__ src,
    const int* __restrict__ dst, const float* __restrict__ dvec,
    const float* __restrict__ w_real, const float* __restrict__ w_imag,
    int* __restrict__ cursor, unsigned long long* __restrict__ records) {
  __shared__ __align__(16) float wstage[8192];  // 32 KB, role-overlaid
  const int bid = blockIdx.x;
  const int tid = threadIdx.x;

  if (bid < PACKB4) {
    const int i = bid * 256 + tid;  // covers N*DIM/4 exactly
    const float4 hr = ((const float4*)h_real)[i];
    const float4 hi = ((const float4*)h_imag)[i];
    uint4 o;
    o.x = pack_bf16x2(hr.x, hi.x);
    o.y = pack_bf16x2(hr.y, hi.y);
    o.z = pack_bf16x2(hr.z, hi.z);
    o.w = pack_bf16x2(hr.w, hi.w);
    ((uint4*)hpack)[i] = o;
    return;
  }

  if (bid < PACKB4 + 64) {
    float* w1s = wstage;
    float* w2s = wstage + 4096;
    for (int i = tid; i < 64 * 64; i += 256) {
      w1s[i] = W1[i];
      w2s[i] = W2[i];
    }
    __syncthreads();
    const int idx = (bid - PACKB4) * 256 + tid;
    if (idx < 128 * 128) {
      const int n = idx >> 7, k = idx & 127;
      float v;
      if (n < 64) {
        v = (k < 64) ? w1s[n * 64 + k] : -w2s[n * 64 + (k - 64)];
      } else {
        const int nn = n - 64;
        if (k < 64) {
          float s = 0.0f;
          for (int j = 0; j < 64; ++j) s += w1s[j * 64 + k] * w2s[nn * 64 + j];
          v = s;
        } else {
          const int kk = k - 64;
          float s = 0.0f;
          for (int j = 0; j < 64; ++j) s += w2s[j * 64 + kk] * w2s[nn * 64 + j];
          v = w1s[nn * 64 + kk] - s;
        }
      }
      At[n * 128 + k] = f2bf(v);
    }
    if (idx < 128) {
      if (idx < 64) {
        cvec[idx] = b1[idx] - b2[idx];
      } else {
        const int nn = idx - 64;
        float s = 0.0f;
        for (int j = 0; j < 64; ++j) s += (b1[j] - b2[j]) * w2s[nn * 64 + j];
        cvec[idx] = s + b1[nn] + b2[nn];
      }
    }
    return;
  }

  // partition role: PTILE edges, 2 passes, chunk reservation into fixed slots
  int* lh = (int*)wstage;          // K1 ints
  int* mybase = lh + K1;           // K1 ints
  const int pb = bid - PACKB4 - 64;
  const int e0 = pb * PTILE;
  const int cnt_t = min(PTILE, N_EDGES - e0);

  for (int i = tid; i < K1; i += 256) lh[i] = 0;
  __syncthreads();

  // pass 1: histogram (dst only, int4)
#pragma unroll
  for (int g = 0; g < PTILE / 1024; ++g) {
    const int off = g * 1024 + tid * 4;
    if (off < cnt_t) {
      const int4 t4 = *(const int4*)(dst + e0 + off);
      atomicAdd(&lh[t4.x >> 8], 1);
      atomicAdd(&lh[t4.y >> 8], 1);
      atomicAdd(&lh[t4.z >> 8], 1);
      atomicAdd(&lh[t4.w >> 8], 1);
    }
  }
  __syncthreads();

  // reservation: one global atomic per non-empty (tile,bucket); reset lh
  for (int b = tid; b < K1; b += 256) {
    const int c = lh[b];
    mybase[b] = c ? atomicAdd(&cursor[b], c) : 0;
    lh[b] = 0;
  }
  __syncthreads();

  // pass 2: emit into the reserved chunk (LDS rank), clamp to slot
#pragma unroll
  for (int g = 0; g < PTILE / 1024; ++g) {
    const int off = g * 1024 + tid * 4;
    if (off < cnt_t) {
      const int e = e0 + off;
      const int4 s4 = *(const int4*)(src + e);
      const int4 t4 = *(const int4*)(dst + e);
      const float4 wr = *(const float4*)(w_real + e);
      const float4 wi = *(const float4*)(w_imag + e);
#define EMIT(SS, TT, WR, WI)                                              \
      {                                                                   \
        const int b = (TT) >> 8;                                          \
        const float ds = dvec[SS];                                        \
        const unsigned lo = (unsigned)(SS) | ((unsigned)((TT) & 255) << 17); \
        const unsigned hi = pack_bf16x2(ds * (WR), ds * (WI));            \
        const int r = atomicAdd(&lh[b], 1);                               \
        const int pos = mybase[b] + r;                                    \
        if (pos < CAP)                                                    \
          records[(size_t)b * CAP + pos] =                                \
              ((unsigned long long)hi << 32) | lo;                        \
      }
      EMIT(s4.x, t4.x, wr.x, wi.x)
      EMIT(s4.y, t4.y, wr.y, wi.y)
      EMIT(s4.z, t4.z, wr.z, wi.z)
      EMIT(s4.w, t4.w, wr.w, wi.w)
#undef EMIT
    }
  }
}

// Pull (r11/r12-verified): place fused into pull. One block per QUARTER-
// bucket (64 nodes). Count pass -> 64-wide shuffle scan -> LDS scatter
// (node-sorted), then quarter-split ILP-4 dot loop (records from LDS,
// hpack gathers from global), then MFMA epilogue. r13 change: bucket range
// = [b*CAP, b*CAP + cursor[b]).
__global__ __launch_bounds__(512, 8) void pull_sorted_kernel(
    const unsigned long long* __restrict__ records,
    const int* __restrict__ cursor, const float* __restrict__ dvec,
    const unsigned* __restrict__ hpack, const unsigned short* __restrict__ At,
    const float* __restrict__ cvec, float* __restrict__ zr_out,
    float* __restrict__ zi_out) {
  __shared__ unsigned long long stageB[QCAP];          // 10.75 KB node-sorted
  __shared__ __align__(16) unsigned short zs[64][136]; // 17 KB
  __shared__ int ncnt[64];
  __shared__ int ncur[64];
  __shared__ int ns[64];
  __shared__ int ne[64];
  const int tid = threadIdx.x;
  const int lane = tid & 63;
  const int wave = tid >> 6;   // 0..7
  const int q4 = lane >> 4;    // quarter-wave id (edge interleave)
  const int m16 = lane & 15;   // dim group: dims 4*m16 .. 4*m16+3
  const int b256 = blockIdx.x >> 2;
  const int qtr = blockIdx.x & 3;
  const int nbase = b256 * 256 + qtr * 64;
  const unsigned* __restrict__ hb = hpack + 4 * m16;

  const int bstart = b256 * CAP;
  const int bend = bstart + min(cursor[b256], CAP);

  if (tid < 64) ncnt[tid] = 0;
  __syncthreads();

  // pass 1: count owned records per local node
  for (int i = bstart + tid; i < bend; i += 512) {
    const unsigned nl = ((unsigned)records[i] >> 17) & 255u;
    if ((int)(nl >> 6) == qtr) atomicAdd(&ncnt[nl & 63], 1);
  }
  __syncthreads();

  // 64-wide shuffle scan in wave 0 -> node starts/ends + scatter cursors
  if (wave == 0) {
    const int c = ncnt[lane];
    int v = c;
#pragma unroll
    for (int off = 1; off < 64; off <<= 1) {
      int t = __shfl_up(v, off);
      if (lane >= off) v += t;
    }
    ns[lane] = v - c;
    ne[lane] = v;
    ncur[lane] = v - c;
  }
  __syncthreads();

  // pass 2: scatter owned records node-sorted into LDS
  for (int i = bstart + tid; i < bend; i += 512) {
    const unsigned long long rec = records[i];
    const unsigned nl = ((unsigned)rec >> 17) & 255u;
    if ((int)(nl >> 6) == qtr) {
      const int pos = atomicAdd(&ncur[nl & 63], 1);
      if (pos < QCAP) stageB[pos] = rec;
    }
  }
  __syncthreads();

#if HAVE_DOT2
#define DOT2(acc, w_, h_)                                                   \
  acc = __builtin_amdgcn_fdot2_f32_bf16(__builtin_bit_cast(bf16x2v, (w_)),  \
                                        __builtin_bit_cast(bf16x2v, (h_)),  \
                                        acc, false)
#else
#define DOT2(acc, w_, h_)                                                   \
  {                                                                         \
    const float _wl = unpack_lo(w_), _wh = unpack_hi(w_);                   \
    const float _hl = unpack_lo(h_), _hh = unpack_hi(h_);                   \
    acc += _wl * _hl + _wh * _hh;                                           \
  }
#endif

#define GATH(RR) \
  (*reinterpret_cast<const uint4*>(hb + (size_t)((unsigned)(RR) & 0x1FFFF) * DIM))

#define DOTS(RR, HV)                                                        \
  {                                                                         \
    const unsigned cf = (unsigned)((RR) >> 32);                             \
    const unsigned wneg = cf ^ 0x80000000u;                                 \
    const unsigned wswp = (cf >> 16) | (cf << 16);                          \
    DOT2(sr0, wneg, (HV).x); DOT2(si0, wswp, (HV).x);                       \
    DOT2(sr1, wneg, (HV).y); DOT2(si1, wswp, (HV).y);                       \
    DOT2(sr2, wneg, (HV).z); DOT2(si2, wswp, (HV).z);                       \
    DOT2(sr3, wneg, (HV).w); DOT2(si3, wswp, (HV).w);                       \
  }

  // dot loop: wave w handles local nodes w*8 .. w*8+7
  for (int j = 0; j < 8; ++j) {
    const int l = wave * 8 + j;
    const int n = nbase + l;
    if (n >= N_NODES) break;  // consecutive: later j also out of range
    const int s = min(ns[l], QCAP);
    const int e = min(ne[l], QCAP);
    const int deg = e - s;

    float sr0 = 0.f, sr1 = 0.f, sr2 = 0.f, sr3 = 0.f;
    float si0 = 0.f, si1 = 0.f, si2 = 0.f, si3 = 0.f;

    int p = s + q4;
    const int nfull = deg >> 2;
    int i = 0;
    for (; i + 4 <= nfull; i += 4) {
      const unsigned long long ra = stageB[p];
      const unsigned long long rb = stageB[p + 4];
      const unsigned long long rc = stageB[p + 8];
      const unsigned long long rd = stageB[p + 12];
      const uint4 ha = GATH(ra);
      const uint4 hbv = GATH(rb);
      const uint4 hc = GATH(rc);
      const uint4 hd = GATH(rd);
      DOTS(ra, ha) DOTS(rb, hbv) DOTS(rc, hc) DOTS(rd, hd)
      p += 16;
    }
    for (; i + 2 <= nfull; i += 2) {
      const unsigned long long ra = stageB[p];
      const unsigned long long rb = stageB[p + 4];
      const uint4 ha = GATH(ra);
      const uint4 hbv = GATH(rb);
      DOTS(ra, ha) DOTS(rb, hbv)
      p += 8;
    }
    if (i < nfull) {
      const unsigned long long ra = stageB[p];
      const uint4 ha = GATH(ra);
      DOTS(ra, ha)
      p += 4;
    }
    if (p < e) {
      const unsigned long long ra = stageB[p];
      const uint4 ha = GATH(ra);
      DOTS(ra, ha)
    }

    // Merge the 4 quarter-partials (lanes L, L^16, L^32, L^48 share dims).
#define QRED(v)                  \
    v += __shfl_xor(v, 16);      \
    v += __shfl_xor(v, 32);
    QRED(sr0) QRED(sr1) QRED(sr2) QRED(sr3)
    QRED(si0) QRED(si1) QRED(si2) QRED(si3)
#undef QRED

    const float dn = dvec[n];
    if (lane < 16) {
      uint2 rv, iv;
      rv.x = pack_bf16x2(dn * sr0, dn * sr1);
      rv.y = pack_bf16x2(dn * sr2, dn * sr3);
      iv.x = pack_bf16x2(dn * si0, dn * si1);
      iv.y = pack_bf16x2(dn * si2, dn * si3);
      *reinterpret_cast<uint2*>(&zs[l][4 * lane]) = rv;
      *reinterpret_cast<uint2*>(&zs[l][64 + 4 * lane]) = iv;
    }
  }
#undef DOTS
#undef GATH
#undef DOT2
  __syncthreads();

  // Epilogue: Out[node][f] = sum_k Zcat[node][k]*A_comb[k][f] + cvec[f].
  // 4 node-groups x 8 feature-tiles; wave w does feature tile w for all 4
  // node groups (verified r9/r11 mapping). Direct strided stores.
  {
    const int m = lane & 15;
    const int q = lane >> 4;
    const int ft = wave;
#pragma unroll
    for (int g = 0; g < 4; ++g) {
      bf16x8 a[4];
#pragma unroll
      for (int c = 0; c < 4; ++c)
        a[c] = *reinterpret_cast<const bf16x8*>(&zs[g * 16 + m][c * 32 + q * 8]);

      f32x4 acc = (f32x4){0.f, 0.f, 0.f, 0.f};
      const unsigned short* brow = At + (size_t)(ft * 16 + m) * 128 + q * 8;
#pragma unroll
      for (int c = 0; c < 4; ++c) {
        bf16x8 bfrag = *reinterpret_cast<const bf16x8*>(brow + c * 32);
        acc = __builtin_amdgcn_mfma_f32_16x16x32_bf16(a[c], bfrag, acc, 0, 0, 0);
      }

      const int nf = ft * 16 + m;
      const float bias = cvec[nf];
      float* outp = (nf < 64) ? zr_out : zi_out;
      const int nnn = nf & 63;
#pragma unroll
      for (int r = 0; r < 4; ++r) {
        const int node = nbase + g * 16 + q * 4 + r;
        if (node < N_NODES) outp[(size_t)node * 64 + nnn] = acc[r] + bias;
      }
    }
  }
}

extern "C" void kernel_launch(void* const* d_in, const int* in_sizes, int n_in,
                              void* d_out, int out_size, void* d_ws, size_t ws_size,
                              hipStream_t stream) {
  const float* h_real = (const float*)d_in[0];
  const float* h_imag = (const float*)d_in[1];
  const float* dvec   = (const float*)d_in[2];
  const float* w_real = (const float*)d_in[3];
  const float* w_imag = (const float*)d_in[4];
  const int*   src    = (const int*)d_in[5];
  const int*   dst    = (const int*)d_in[6];
  const float* W1     = (const float*)d_in[7];
  const float* b1     = (const float*)d_in[8];
  const float* W2     = (const float*)d_in[9];
  const float* b2     = (const float*)d_in[10];

  char* ws = (char*)d_ws;
  unsigned short* At = (unsigned short*)ws;                          // 32 KB
  float* cvec = (float*)(ws + 128 * 128 * 2);                        // 1 KB
  unsigned long long* records = (unsigned long long*)(ws + 33792);   // 14.0 MB
  unsigned* hpack =
      (unsigned*)(ws + 33792 + (size_t)K1 * CAP * 8);                // 25.6 MB
  int* cursor =
      (int*)(ws + 33792 + (size_t)K1 * CAP * 8 + (size_t)N_NODES * DIM * 4);

  float* zr_out = (float*)d_out;
  float* zi_out = zr_out + (size_t)N_NODES * DIM;

  hipMemsetAsync(cursor, 0, (size_t)K1 * sizeof(int), stream);
  mega_kernel<<<PACKB4 + 64 + PARTB, 256, 0, stream>>>(
      h_real, h_imag, (unsigned*)hpack, W1, b1, W2, b2, At, cvec,
      src, dst, dvec, w_real, w_imag, cursor, records);
  pull_sorted_kernel<<<K1 * 4, 512, 0, stream>>>(
      records, cursor, dvec, hpack, At, cvec, zr_out, zi_out);
}

// Round 14
// 264.336 us; speedup vs baseline: 1.0865x; 1.0865x over previous
//
#include <hip/hip_runtime.h>
#include <hip/hip_bf16.h>

#define N_NODES 100000
#define N_EDGES 1600000
#define DIM 64

#define K1 ((N_NODES + 255) / 256)               // 391 buckets of 256 nodes
#define PTILE 2048
#define PARTB ((N_EDGES + PTILE - 1) / PTILE)    // 782 partition-role blocks
#define PACKV (N_NODES * DIM / 4)                // 1.6M float4 elements
#define PACKB ((PACKV + 1023) / 1024)            // 1563 pack-role blocks
#define CAP 4480                                 // bucket slot: mean 4096 + 6 sigma
#define QCAP 1344                                // quarter-bucket: mean 1024 + 10 sigma

typedef __attribute__((ext_vector_type(8))) short bf16x8;
typedef __attribute__((ext_vector_type(4))) float f32x4;

#if defined(__has_builtin)
#if __has_builtin(__builtin_amdgcn_fdot2_f32_bf16)
#define HAVE_DOT2 1
typedef __attribute__((ext_vector_type(2))) __bf16 bf16x2v;
#endif
#endif

// ---------------- ws layout ----------------
// At      : 32 KB bf16 (combined epilogue matrix, transposed)
// cvec    : 1 KB
// records : K1 * CAP * 8 B fixed bucket slots (u64 {hi=bf16x2 coef,
//           lo=src | dst_local<<17}); bucket b owns [b*CAP, b*CAP+cursor[b]).
//           Within-bucket order ARBITRARY — pull re-sorts in LDS.
// hpack   : N*DIM*4B ({bf16 hr, bf16 hi} interleaved)
// cursor  : K1 ints (memset 0; bumped by partition reservation; final = count)

__device__ __forceinline__ unsigned pack_bf16x2(float lo, float hi) {
  unsigned ulo = (unsigned)__hip_bfloat16_raw(__float2bfloat16(lo)).x;
  unsigned uhi = (unsigned)__hip_bfloat16_raw(__float2bfloat16(hi)).x;
  return ulo | (uhi << 16);
}
__device__ __forceinline__ float unpack_lo(unsigned u) {
  return __int_as_float((int)(u << 16));
}
__device__ __forceinline__ float unpack_hi(unsigned u) {
  return __int_as_float((int)(u & 0xFFFF0000u));
}
__device__ __forceinline__ unsigned short f2bf(float x) {
  return __hip_bfloat16_raw(__float2bfloat16(x)).x;
}

// MEGA kernel v2 (r14): partition role FIRST (782 blocks, the long pole),
// At role middle (global W reads — r12 showed LDS staging buys nothing),
// pack role last (1563 dense blocks). Static LDS only 3.1 KB (partition's
// lh/mybase) — no occupancy cap on any role.
__global__ __launch_bounds__(256) void mega_kernel(
    const float* __restrict__ h_real, const float* __restrict__ h_imag,
    unsigned* __restrict__ hpack, const float* __restrict__ W1,
    const float* __restrict__ b1, const float* __restrict__ W2,
    const float* __restrict__ b2, unsigned short* __restrict__ At,
    float* __restrict__ cvec, const int* __restrict__ src,
    const int* __restrict__ dst, const float* __restrict__ dvec,
    const float* __restrict__ w_real, const float* __restrict__ w_imag,
    int* __restrict__ cursor, unsigned long long* __restrict__ records) {
  __shared__ int lh[K1];
  __shared__ int mybase[K1];
  const int bid = blockIdx.x;
  const int tid = threadIdx.x;

  if (bid < PARTB) {
    // ---- partition role: PTILE edges, hist -> reserve -> emit ----
    const int e0 = bid * PTILE;
    const int cnt_t = min(PTILE, N_EDGES - e0);

    for (int i = tid; i < K1; i += 256) lh[i] = 0;
    __syncthreads();

#pragma unroll
    for (int g = 0; g < PTILE / 1024; ++g) {
      const int off = g * 1024 + tid * 4;
      if (off < cnt_t) {
        const int4 t4 = *(const int4*)(dst + e0 + off);
        atomicAdd(&lh[t4.x >> 8], 1);
        atomicAdd(&lh[t4.y >> 8], 1);
        atomicAdd(&lh[t4.z >> 8], 1);
        atomicAdd(&lh[t4.w >> 8], 1);
      }
    }
    __syncthreads();

    for (int b = tid; b < K1; b += 256) {
      const int c = lh[b];
      mybase[b] = c ? atomicAdd(&cursor[b], c) : 0;
      lh[b] = 0;
    }
    __syncthreads();

#pragma unroll
    for (int g = 0; g < PTILE / 1024; ++g) {
      const int off = g * 1024 + tid * 4;
      if (off < cnt_t) {
        const int e = e0 + off;
        const int4 s4 = *(const int4*)(src + e);
        const int4 t4 = *(const int4*)(dst + e);
        const float4 wr = *(const float4*)(w_real + e);
        const float4 wi = *(const float4*)(w_imag + e);
#define EMIT(SS, TT, WR, WI)                                              \
        {                                                                 \
          const int b = (TT) >> 8;                                        \
          const float ds = dvec[SS];                                      \
          const unsigned lo =                                             \
              (unsigned)(SS) | ((unsigned)((TT) & 255) << 17);            \
          const unsigned hi = pack_bf16x2(ds * (WR), ds * (WI));          \
          const int r = atomicAdd(&lh[b], 1);                             \
          const int pos = mybase[b] + r;                                  \
          if (pos < CAP)                                                  \
            records[(size_t)b * CAP + pos] =                              \
                ((unsigned long long)hi << 32) | lo;                      \
        }
        EMIT(s4.x, t4.x, wr.x, wi.x)
        EMIT(s4.y, t4.y, wr.y, wi.y)
        EMIT(s4.z, t4.z, wr.z, wi.z)
        EMIT(s4.w, t4.w, wr.w, wi.w)
#undef EMIT
      }
    }
    return;
  }

  if (bid < PARTB + 64) {
    // ---- At/cvec role (r11-verified, global W reads) ----
    const int idx = (bid - PARTB) * 256 + tid;
    if (idx < 128 * 128) {
      const int n = idx >> 7, k = idx & 127;
      float v;
      if (n < 64) {
        v = (k < 64) ? W1[n * 64 + k] : -W2[n * 64 + (k - 64)];
      } else {
        const int nn = n - 64;
        if (k < 64) {
          float s = 0.0f;
          for (int j = 0; j < 64; ++j) s += W1[j * 64 + k] * W2[nn * 64 + j];
          v = s;
        } else {
          const int kk = k - 64;
          float s = 0.0f;
          for (int j = 0; j < 64; ++j) s += W2[j * 64 + kk] * W2[nn * 64 + j];
          v = W1[nn * 64 + kk] - s;
        }
      }
      At[n * 128 + k] = f2bf(v);
    }
    if (idx < 128) {
      if (idx < 64) {
        cvec[idx] = b1[idx] - b2[idx];
      } else {
        const int nn = idx - 64;
        float s = 0.0f;
        for (int j = 0; j < 64; ++j) s += (b1[j] - b2[j]) * W2[nn * 64 + j];
        cvec[idx] = s + b1[nn] + b2[nn];
      }
    }
    return;
  }

  // ---- pack role: 1024 float4 per block (4 per thread, coalesced) ----
  {
    const int pb = bid - PARTB - 64;
    const int base = pb * 1024;
#pragma unroll
    for (int k = 0; k < 4; ++k) {
      const int i = base + k * 256 + tid;
      if (i < PACKV) {
        const float4 hr = ((const float4*)h_real)[i];
        const float4 hi = ((const float4*)h_imag)[i];
        uint4 o;
        o.x = pack_bf16x2(hr.x, hi.x);
        o.y = pack_bf16x2(hr.y, hi.y);
        o.z = pack_bf16x2(hr.z, hi.z);
        o.w = pack_bf16x2(hr.w, hi.w);
        ((uint4*)hpack)[i] = o;
      }
    }
  }
}

// Pull (r11/r12/r13-verified): place fused into pull. One block per QUARTER-
// bucket (64 nodes). Count pass -> 64-wide shuffle scan -> LDS scatter
// (node-sorted), then quarter-split ILP-4 dot loop (records from LDS,
// hpack gathers from global), then MFMA epilogue. Bucket range =
// [b*CAP, b*CAP + cursor[b]).
__global__ __launch_bounds__(512, 8) void pull_sorted_kernel(
    const unsigned long long* __restrict__ records,
    const int* __restrict__ cursor, const float* __restrict__ dvec,
    const unsigned* __restrict__ hpack, const unsigned short* __restrict__ At,
    const float* __restrict__ cvec, float* __restrict__ zr_out,
    float* __restrict__ zi_out) {
  __shared__ unsigned long long stageB[QCAP];          // 10.75 KB node-sorted
  __shared__ __align__(16) unsigned short zs[64][136]; // 17 KB
  __shared__ int ncnt[64];
  __shared__ int ncur[64];
  __shared__ int ns[64];
  __shared__ int ne[64];
  const int tid = threadIdx.x;
  const int lane = tid & 63;
  const int wave = tid >> 6;   // 0..7
  const int q4 = lane >> 4;    // quarter-wave id (edge interleave)
  const int m16 = lane & 15;   // dim group: dims 4*m16 .. 4*m16+3
  const int b256 = blockIdx.x >> 2;
  const int qtr = blockIdx.x & 3;
  const int nbase = b256 * 256 + qtr * 64;
  const unsigned* __restrict__ hb = hpack + 4 * m16;

  const int bstart = b256 * CAP;
  const int bend = bstart + min(cursor[b256], CAP);

  if (tid < 64) ncnt[tid] = 0;
  __syncthreads();

  // pass 1: count owned records per local node
  for (int i = bstart + tid; i < bend; i += 512) {
    const unsigned nl = ((unsigned)records[i] >> 17) & 255u;
    if ((int)(nl >> 6) == qtr) atomicAdd(&ncnt[nl & 63], 1);
  }
  __syncthreads();

  // 64-wide shuffle scan in wave 0 -> node starts/ends + scatter cursors
  if (wave == 0) {
    const int c = ncnt[lane];
    int v = c;
#pragma unroll
    for (int off = 1; off < 64; off <<= 1) {
      int t = __shfl_up(v, off);
      if (lane >= off) v += t;
    }
    ns[lane] = v - c;
    ne[lane] = v;
    ncur[lane] = v - c;
  }
  __syncthreads();

  // pass 2: scatter owned records node-sorted into LDS
  for (int i = bstart + tid; i < bend; i += 512) {
    const unsigned long long rec = records[i];
    const unsigned nl = ((unsigned)rec >> 17) & 255u;
    if ((int)(nl >> 6) == qtr) {
      const int pos = atomicAdd(&ncur[nl & 63], 1);
      if (pos < QCAP) stageB[pos] = rec;
    }
  }
  __syncthreads();

#if HAVE_DOT2
#define DOT2(acc, w_, h_)                                                   \
  acc = __builtin_amdgcn_fdot2_f32_bf16(__builtin_bit_cast(bf16x2v, (w_)),  \
                                        __builtin_bit_cast(bf16x2v, (h_)),  \
                                        acc, false)
#else
#define DOT2(acc, w_, h_)                                                   \
  {                                                                         \
    const float _wl = unpack_lo(w_), _wh = unpack_hi(w_);                   \
    const float _hl = unpack_lo(h_), _hh = unpack_hi(h_);                   \
    acc += _wl * _hl + _wh * _hh;                                           \
  }
#endif

#define GATH(RR) \
  (*reinterpret_cast<const uint4*>(hb + (size_t)((unsigned)(RR) & 0x1FFFF) * DIM))

#define DOTS(RR, HV)                                                        \
  {                                                                         \
    const unsigned cf = (unsigned)((RR) >> 32);                             \
    const unsigned wneg = cf ^ 0x80000000u;                                 \
    const unsigned wswp = (cf >> 16) | (cf << 16);                          \
    DOT2(sr0, wneg, (HV).x); DOT2(si0, wswp, (HV).x);                       \
    DOT2(sr1, wneg, (HV).y); DOT2(si1, wswp, (HV).y);                       \
    DOT2(sr2, wneg, (HV).z); DOT2(si2, wswp, (HV).z);                       \
    DOT2(sr3, wneg, (HV).w); DOT2(si3, wswp, (HV).w);                       \
  }

  // dot loop: wave w handles local nodes w*8 .. w*8+7
  for (int j = 0; j < 8; ++j) {
    const int l = wave * 8 + j;
    const int n = nbase + l;
    if (n >= N_NODES) break;  // consecutive: later j also out of range
    const int s = min(ns[l], QCAP);
    const int e = min(ne[l], QCAP);
    const int deg = e - s;

    float sr0 = 0.f, sr1 = 0.f, sr2 = 0.f, sr3 = 0.f;
    float si0 = 0.f, si1 = 0.f, si2 = 0.f, si3 = 0.f;

    int p = s + q4;
    const int nfull = deg >> 2;
    int i = 0;
    for (; i + 4 <= nfull; i += 4) {
      const unsigned long long ra = stageB[p];
      const unsigned long long rb = stageB[p + 4];
      const unsigned long long rc = stageB[p + 8];
      const unsigned long long rd = stageB[p + 12];
      const uint4 ha = GATH(ra);
      const uint4 hbv = GATH(rb);
      const uint4 hc = GATH(rc);
      const uint4 hd = GATH(rd);
      DOTS(ra, ha) DOTS(rb, hbv) DOTS(rc, hc) DOTS(rd, hd)
      p += 16;
    }
    for (; i + 2 <= nfull; i += 2) {
      const unsigned long long ra = stageB[p];
      const unsigned long long rb = stageB[p + 4];
      const uint4 ha = GATH(ra);
      const uint4 hbv = GATH(rb);
      DOTS(ra, ha) DOTS(rb, hbv)
      p += 8;
    }
    if (i < nfull) {
      const unsigned long long ra = stageB[p];
      const uint4 ha = GATH(ra);
      DOTS(ra, ha)
      p += 4;
    }
    if (p < e) {
      const unsigned long long ra = stageB[p];
      const uint4 ha = GATH(ra);
      DOTS(ra, ha)
    }

    // Merge the 4 quarter-partials (lanes L, L^16, L^32, L^48 share dims).
#define QRED(v)                  \
    v += __shfl_xor(v, 16);      \
    v += __shfl_xor(v, 32);
    QRED(sr0) QRED(sr1) QRED(sr2) QRED(sr3)
    QRED(si0) QRED(si1) QRED(si2) QRED(si3)
#undef QRED

    const float dn = dvec[n];
    if (lane < 16) {
      uint2 rv, iv;
      rv.x = pack_bf16x2(dn * sr0, dn * sr1);
      rv.y = pack_bf16x2(dn * sr2, dn * sr3);
      iv.x = pack_bf16x2(dn * si0, dn * si1);
      iv.y = pack_bf16x2(dn * si2, dn * si3);
      *reinterpret_cast<uint2*>(&zs[l][4 * lane]) = rv;
      *reinterpret_cast<uint2*>(&zs[l][64 + 4 * lane]) = iv;
    }
  }
#undef DOTS
#undef GATH
#undef DOT2
  __syncthreads();

  // Epilogue: Out[node][f] = sum_k Zcat[node][k]*A_comb[k][f] + cvec[f].
  // 4 node-groups x 8 feature-tiles; wave w does feature tile w for all 4
  // node groups (verified r9/r11 mapping). Direct strided stores.
  {
    const int m = lane & 15;
    const int q = lane >> 4;
    const int ft = wave;
#pragma unroll
    for (int g = 0; g < 4; ++g) {
      bf16x8 a[4];
#pragma unroll
      for (int c = 0; c < 4; ++c)
        a[c] = *reinterpret_cast<const bf16x8*>(&zs[g * 16 + m][c * 32 + q * 8]);

      f32x4 acc = (f32x4){0.f, 0.f, 0.f, 0.f};
      const unsigned short* brow = At + (size_t)(ft * 16 + m) * 128 + q * 8;
#pragma unroll
      for (int c = 0; c < 4; ++c) {
        bf16x8 bfrag = *reinterpret_cast<const bf16x8*>(brow + c * 32);
        acc = __builtin_amdgcn_mfma_f32_16x16x32_bf16(a[c], bfrag, acc, 0, 0, 0);
      }

      const int nf = ft * 16 + m;
      const float bias = cvec[nf];
      float* outp = (nf < 64) ? zr_out : zi_out;
      const int nnn = nf & 63;
#pragma unroll
      for (int r = 0; r < 4; ++r) {
        const int node = nbase + g * 16 + q * 4 + r;
        if (node < N_NODES) outp[(size_t)node * 64 + nnn] = acc[r] + bias;
      }
    }
  }
}

extern "C" void kernel_launch(void* const* d_in, const int* in_sizes, int n_in,
                              void* d_out, int out_size, void* d_ws, size_t ws_size,
                              hipStream_t stream) {
  const float* h_real = (const float*)d_in[0];
  const float* h_imag = (const float*)d_in[1];
  const float* dvec   = (const float*)d_in[2];
  const float* w_real = (const float*)d_in[3];
  const float* w_imag = (const float*)d_in[4];
  const int*   src    = (const int*)d_in[5];
  const int*   dst    = (const int*)d_in[6];
  const float* W1     = (const float*)d_in[7];
  const float* b1     = (const float*)d_in[8];
  const float* W2     = (const float*)d_in[9];
  const float* b2     = (const float*)d_in[10];

  char* ws = (char*)d_ws;
  unsigned short* At = (unsigned short*)ws;                          // 32 KB
  float* cvec = (float*)(ws + 128 * 128 * 2);                        // 1 KB
  unsigned long long* records = (unsigned long long*)(ws + 33792);   // 14.0 MB
  unsigned* hpack =
      (unsigned*)(ws + 33792 + (size_t)K1 * CAP * 8);                // 25.6 MB
  int* cursor =
      (int*)(ws + 33792 + (size_t)K1 * CAP * 8 + (size_t)N_NODES * DIM * 4);

  float* zr_out = (float*)d_out;
  float* zi_out = zr_out + (size_t)N_NODES * DIM;

  hipMemsetAsync(cursor, 0, (size_t)K1 * sizeof(int), stream);
  mega_kernel<<<PARTB + 64 + PACKB, 256, 0, stream>>>(
      h_real, h_imag, (unsigned*)hpack, W1, b1, W2, b2, At, cvec,
      src, dst, dvec, w_real, w_imag, cursor, records);
  pull_sorted_kernel<<<K1 * 4, 512, 0, stream>>>(
      records, cursor, dvec, hpack, At, cvec, zr_out, zi_out);
}

// Round 15
// 247.289 us; speedup vs baseline: 1.1614x; 1.0689x over previous
//
#include <hip/hip_runtime.h>
#include <hip/hip_bf16.h>

#define N_NODES 100000
#define N_EDGES 1600000
#define DIM 64

#define TILE 4096
#define B1 ((N_EDGES + TILE - 1) / TILE)        // 391 partition blocks
#define K1 ((N_NODES + 255) / 256)              // 391 buckets of 256 nodes
#define NCOUNTS (K1 * B1)                       // 152881
#define SCAN_BLOCK 1024
#define NSB ((NCOUNTS + SCAN_BLOCK - 1) / SCAN_BLOCK)  // 150
#define PACKB4 ((N_NODES * DIM / 4 + 255) / 256) // 6250 (exact: N*DIM = 6.4M)
#define QCAP 1344                               // quarter-bucket: mean 1024, sd 32 -> +10 sigma

typedef __attribute__((ext_vector_type(8))) short bf16x8;
typedef __attribute__((ext_vector_type(4))) float f32x4;

#if defined(__has_builtin)
#if __has_builtin(__builtin_amdgcn_fdot2_f32_bf16)
#define HAVE_DOT2 1
typedef __attribute__((ext_vector_type(2))) __bf16 bf16x2v;
#endif
#endif

// ---------------- ws layout ----------------
// At      : 32 KB bf16 (combined epilogue matrix, transposed)
// cvec    : 1 KB
// records : E * 8 B  (u64 {hi=bf16x2 coef, lo=src | dst_local<<17}); written
//           bucket-grouped by partition. NO global node-sort: pull_sorted
//           builds the node order in LDS per quarter-bucket (place fused).
// hpack   : N*DIM*4B ({bf16 hr, bf16 hi} interleaved)
// counts  : NCOUNTS ints (hist -> in-place BLOCK-LOCAL exclusive prefix;
//           global offset = counts[ci] + bpre[ci>>10])
// bsum/bpre : NSB ints

__device__ __forceinline__ unsigned pack_bf16x2(float lo, float hi) {
  unsigned ulo = (unsigned)__hip_bfloat16_raw(__float2bfloat16(lo)).x;
  unsigned uhi = (unsigned)__hip_bfloat16_raw(__float2bfloat16(hi)).x;
  return ulo | (uhi << 16);
}
__device__ __forceinline__ float unpack_lo(unsigned u) {
  return __int_as_float((int)(u << 16));
}
__device__ __forceinline__ float unpack_hi(unsigned u) {
  return __int_as_float((int)(u & 0xFFFF0000u));
}
__device__ __forceinline__ unsigned short f2bf(float x) {
  return __hip_bfloat16_raw(__float2bfloat16(x)).x;
}

// Fused setup (r8-verified): pack_h (float4-vectorized), combined epilogue
// operator, per-(bucket,tile) LDS histogram.
__global__ __launch_bounds__(256) void setup_fused_kernel(
    const float* __restrict__ h_real, const float* __restrict__ h_imag,
    unsigned* __restrict__ hpack, const float* __restrict__ W1,
    const float* __restrict__ b1, const float* __restrict__ W2,
    const float* __restrict__ b2, unsigned short* __restrict__ At,
    float* __restrict__ cvec, const int* __restrict__ dst,
    int* __restrict__ counts) {
  const int bid = blockIdx.x;
  const int tid = threadIdx.x;
  if (bid < PACKB4) {
    const int i = bid * 256 + tid;  // covers N*DIM/4 exactly
    const float4 hr = ((const float4*)h_real)[i];
    const float4 hi = ((const float4*)h_imag)[i];
    uint4 o;
    o.x = pack_bf16x2(hr.x, hi.x);
    o.y = pack_bf16x2(hr.y, hi.y);
    o.z = pack_bf16x2(hr.z, hi.z);
    o.w = pack_bf16x2(hr.w, hi.w);
    ((uint4*)hpack)[i] = o;
    return;
  }
  if (bid < PACKB4 + 64) {
    const int idx = (bid - PACKB4) * 256 + tid;
    if (idx < 128 * 128) {
      const int n = idx >> 7, k = idx & 127;
      float v;
      if (n < 64) {
        v = (k < 64) ? W1[n * 64 + k] : -W2[n * 64 + (k - 64)];
      } else {
        const int nn = n - 64;
        if (k < 64) {
          float s = 0.0f;
          for (int j = 0; j < 64; ++j) s += W1[j * 64 + k] * W2[nn * 64 + j];
          v = s;
        } else {
          const int kk = k - 64;
          float s = 0.0f;
          for (int j = 0; j < 64; ++j) s += W2[j * 64 + kk] * W2[nn * 64 + j];
          v = W1[nn * 64 + kk] - s;
        }
      }
      At[n * 128 + k] = f2bf(v);
    }
    if (idx < 128) {
      if (idx < 64) {
        cvec[idx] = b1[idx] - b2[idx];
      } else {
        const int nn = idx - 64;
        float s = 0.0f;
        for (int j = 0; j < 64; ++j) s += (b1[j] - b2[j]) * W2[nn * 64 + j];
        cvec[idx] = s + b1[nn] + b2[nn];
      }
    }
    return;
  }
  // histogram role (LDS-local, per tile)
  __shared__ int lh[K1];
  const int hb = bid - PACKB4 - 64;
  for (int i = tid; i < K1; i += 256) lh[i] = 0;
  __syncthreads();
  const int e0 = hb * TILE;
  const int e1 = min(e0 + TILE, N_EDGES);
  for (int e = e0 + tid; e < e1; e += 256) atomicAdd(&lh[dst[e] >> 8], 1);
  __syncthreads();
  for (int b = tid; b < K1; b += 256) counts[b * B1 + hb] = lh[b];
}

// In-place: counts -> BLOCK-LOCAL exclusive prefix; bsum[blk] = block total.
__global__ __launch_bounds__(SCAN_BLOCK) void scan1_kernel(
    int* __restrict__ cnt, int* __restrict__ bsum) {
  __shared__ int wsum[16];
  const int tid = threadIdx.x;
  const int lane = tid & 63;
  const int w = tid >> 6;
  const int i = blockIdx.x * SCAN_BLOCK + tid;
  const int orig = (i < NCOUNTS) ? cnt[i] : 0;
  int v = orig;
#pragma unroll
  for (int off = 1; off < 64; off <<= 1) {
    int t = __shfl_up(v, off);
    if (lane >= off) v += t;
  }
  if (lane == 63) wsum[w] = v;
  __syncthreads();
  if (w == 0) {
    int s = (lane < 16) ? wsum[lane] : 0;
#pragma unroll
    for (int off = 1; off < 16; off <<= 1) {
      int t = __shfl_up(s, off);
      if (lane >= off) s += t;
    }
    if (lane < 16) wsum[lane] = s;
  }
  __syncthreads();
  const int wex = (w == 0) ? 0 : wsum[w - 1];
  if (i < NCOUNTS) cnt[i] = wex + v - orig;  // exclusive (block-local)
  if (tid == SCAN_BLOCK - 1) bsum[blockIdx.x] = wex + v;
}

// Scan of the NSB block sums -> exclusive bpre.
__global__ __launch_bounds__(256) void scan2_kernel(
    const int* __restrict__ bsum, int* __restrict__ bpre) {
  __shared__ int wsum[4];
  const int tid = threadIdx.x;
  const int lane = tid & 63;
  const int w = tid >> 6;
  const int orig = (tid < NSB) ? bsum[tid] : 0;
  int v = orig;
#pragma unroll
  for (int off = 1; off < 64; off <<= 1) {
    int t = __shfl_up(v, off);
    if (lane >= off) v += t;
  }
  if (lane == 63) wsum[w] = v;
  __syncthreads();
  if (w == 0) {
    int s = (lane < 4) ? wsum[lane] : 0;
#pragma unroll
    for (int off = 1; off < 4; off <<= 1) {
      int t = __shfl_up(s, off);
      if (lane >= off) s += t;
    }
    if (lane < 4) wsum[lane] = s;
  }
  __syncthreads();
  const int wex = (w == 0) ? 0 : wsum[w - 1];
  if (tid < NSB) bpre[tid] = wex + v - orig;  // exclusive
}

// Partition (r9-verified, staged): stage tile in LDS sorted by bucket, write
// contiguous runs. Global offset = coffs[ci] + bpre[ci>>10].
__global__ __launch_bounds__(512) void partition_kernel(
    const int* __restrict__ src, const int* __restrict__ dst,
    const float* __restrict__ dvec,
    const float* __restrict__ w_real, const float* __restrict__ w_imag,
    const int* __restrict__ coffs, const int* __restrict__ bpre,
    unsigned long long* __restrict__ records) {
  __shared__ unsigned long long stage[TILE];  // 32 KB
  __shared__ unsigned short sb[TILE];         // 8 KB
  __shared__ int lhist[512];
  __shared__ int lbase[K1];
  __shared__ int lcur[K1];
  __shared__ int gbase[K1];
  __shared__ int wsum[8];
  const int tid = threadIdx.x;
  const int lane = tid & 63;
  const int w = tid >> 6;
  const int blk = blockIdx.x;
  const int e0 = blk * TILE;
  const int cnt_t = min(TILE, N_EDGES - e0);

  lhist[tid] = 0;
  __syncthreads();
  for (int j = tid; j < cnt_t; j += 512) atomicAdd(&lhist[dst[e0 + j] >> 8], 1);
  __syncthreads();
  const int myc = lhist[tid];
  int v = myc;
#pragma unroll
  for (int off = 1; off < 64; off <<= 1) {
    int t = __shfl_up(v, off);
    if (lane >= off) v += t;
  }
  if (lane == 63) wsum[w] = v;
  __syncthreads();
  if (w == 0) {
    int s = (lane < 8) ? wsum[lane] : 0;
#pragma unroll
    for (int off = 1; off < 8; off <<= 1) {
      int t = __shfl_up(s, off);
      if (lane >= off) s += t;
    }
    if (lane < 8) wsum[lane] = s;
  }
  __syncthreads();
  const int ex = v + ((w == 0) ? 0 : wsum[w - 1]) - myc;  // exclusive
  if (tid < K1) {
    lbase[tid] = ex;
    lcur[tid] = ex;
    const int ci = tid * B1 + blk;
    gbase[tid] = coffs[ci] + bpre[ci >> 10];
  }
  __syncthreads();

  for (int j = tid; j < cnt_t; j += 512) {
    const int e = e0 + j;
    const int t = dst[e];
    const int s = src[e];
    const int b = t >> 8;
    const float ds = dvec[s];
    const unsigned lo = (unsigned)s | ((unsigned)(t & 255) << 17);
    const unsigned hi = pack_bf16x2(ds * w_real[e], ds * w_imag[e]);
    const int r = atomicAdd(&lcur[b], 1);
    stage[r] = ((unsigned long long)hi << 32) | lo;
    sb[r] = (unsigned short)b;
  }
  __syncthreads();
  for (int i = tid; i < cnt_t; i += 512) {
    const int b = sb[i];
    records[gbase[b] + (i - lbase[b])] = stage[i];
  }
}

// Pull v6 (r11-verified): place FUSED into pull. One block per QUARTER-
// bucket (64 nodes). Two passes over the bucket's contiguous record range
// build a node-sorted LDS copy (count -> 64-wide shuffle scan -> scatter);
// then the r9-verified quarter-split ILP-4 dot loop runs with records read
// from LDS (broadcast) and hpack gathers from global; then the verified
// MFMA epilogue with direct stores.
__global__ __launch_bounds__(512, 8) void pull_sorted_kernel(
    const unsigned long long* __restrict__ records,
    const int* __restrict__ coffs, const int* __restrict__ bpre,
    const float* __restrict__ dvec, const unsigned* __restrict__ hpack,
    const unsigned short* __restrict__ At, const float* __restrict__ cvec,
    float* __restrict__ zr_out, float* __restrict__ zi_out) {
  __shared__ unsigned long long stageB[QCAP];          // 10.75 KB node-sorted
  __shared__ __align__(16) unsigned short zs[64][136]; // 17 KB
  __shared__ int ncnt[64];
  __shared__ int ncur[64];
  __shared__ int ns[64];
  __shared__ int ne[64];
  const int tid = threadIdx.x;
  const int lane = tid & 63;
  const int wave = tid >> 6;   // 0..7
  const int q4 = lane >> 4;    // quarter-wave id (edge interleave)
  const int m16 = lane & 15;   // dim group: dims 4*m16 .. 4*m16+3
  const int b256 = blockIdx.x >> 2;
  const int qtr = blockIdx.x & 3;
  const int nbase = b256 * 256 + qtr * 64;
  const unsigned* __restrict__ hb = hpack + 4 * m16;

  // bucket record range (global offsets via coffs + bpre)
  const int ci0 = b256 * B1;
  const int bstart = coffs[ci0] + bpre[ci0 >> 10];
  int bend;
  if (b256 == K1 - 1) {
    bend = N_EDGES;
  } else {
    const int ci1 = (b256 + 1) * B1;
    bend = coffs[ci1] + bpre[ci1 >> 10];
  }

  if (tid < 64) ncnt[tid] = 0;
  __syncthreads();

  // pass 1: count owned records per local node
  for (int i = bstart + tid; i < bend; i += 512) {
    const unsigned nl = ((unsigned)records[i] >> 17) & 255u;
    if ((int)(nl >> 6) == qtr) atomicAdd(&ncnt[nl & 63], 1);
  }
  __syncthreads();

  // 64-wide shuffle scan in wave 0 -> node starts/ends + scatter cursors
  if (wave == 0) {
    const int c = ncnt[lane];
    int v = c;
#pragma unroll
    for (int off = 1; off < 64; off <<= 1) {
      int t = __shfl_up(v, off);
      if (lane >= off) v += t;
    }
    ns[lane] = v - c;
    ne[lane] = v;
    ncur[lane] = v - c;
  }
  __syncthreads();

  // pass 2: scatter owned records node-sorted into LDS
  for (int i = bstart + tid; i < bend; i += 512) {
    const unsigned long long rec = records[i];
    const unsigned nl = ((unsigned)rec >> 17) & 255u;
    if ((int)(nl >> 6) == qtr) {
      const int pos = atomicAdd(&ncur[nl & 63], 1);
      if (pos < QCAP) stageB[pos] = rec;
    }
  }
  __syncthreads();

#if HAVE_DOT2
#define DOT2(acc, w_, h_)                                                   \
  acc = __builtin_amdgcn_fdot2_f32_bf16(__builtin_bit_cast(bf16x2v, (w_)),  \
                                        __builtin_bit_cast(bf16x2v, (h_)),  \
                                        acc, false)
#else
#define DOT2(acc, w_, h_)                                                   \
  {                                                                         \
    const float _wl = unpack_lo(w_), _wh = unpack_hi(w_);                   \
    const float _hl = unpack_lo(h_), _hh = unpack_hi(h_);                   \
    acc += _wl * _hl + _wh * _hh;                                           \
  }
#endif

#define GATH(RR) \
  (*reinterpret_cast<const uint4*>(hb + (size_t)((unsigned)(RR) & 0x1FFFF) * DIM))

#define DOTS(RR, HV)                                                        \
  {                                                                         \
    const unsigned cf = (unsigned)((RR) >> 32);                             \
    const unsigned wneg = cf ^ 0x80000000u;                                 \
    const unsigned wswp = (cf >> 16) | (cf << 16);                          \
    DOT2(sr0, wneg, (HV).x); DOT2(si0, wswp, (HV).x);                       \
    DOT2(sr1, wneg, (HV).y); DOT2(si1, wswp, (HV).y);                       \
    DOT2(sr2, wneg, (HV).z); DOT2(si2, wswp, (HV).z);                       \
    DOT2(sr3, wneg, (HV).w); DOT2(si3, wswp, (HV).w);                       \
  }

  // dot loop: wave w handles local nodes w*8 .. w*8+7
  for (int j = 0; j < 8; ++j) {
    const int l = wave * 8 + j;
    const int n = nbase + l;
    if (n >= N_NODES) break;  // consecutive: later j also out of range
    const int s = min(ns[l], QCAP);
    const int e = min(ne[l], QCAP);
    const int deg = e - s;

    float sr0 = 0.f, sr1 = 0.f, sr2 = 0.f, sr3 = 0.f;
    float si0 = 0.f, si1 = 0.f, si2 = 0.f, si3 = 0.f;

    int p = s + q4;
    const int nfull = deg >> 2;
    int i = 0;
    for (; i + 4 <= nfull; i += 4) {
      const unsigned long long ra = stageB[p];
      const unsigned long long rb = stageB[p + 4];
      const unsigned long long rc = stageB[p + 8];
      const unsigned long long rd = stageB[p + 12];
      const uint4 ha = GATH(ra);
      const uint4 hbv = GATH(rb);
      const uint4 hc = GATH(rc);
      const uint4 hd = GATH(rd);
      DOTS(ra, ha) DOTS(rb, hbv) DOTS(rc, hc) DOTS(rd, hd)
      p += 16;
    }
    for (; i + 2 <= nfull; i += 2) {
      const unsigned long long ra = stageB[p];
      const unsigned long long rb = stageB[p + 4];
      const uint4 ha = GATH(ra);
      const uint4 hbv = GATH(rb);
      DOTS(ra, ha) DOTS(rb, hbv)
      p += 8;
    }
    if (i < nfull) {
      const unsigned long long ra = stageB[p];
      const uint4 ha = GATH(ra);
      DOTS(ra, ha)
      p += 4;
    }
    if (p < e) {
      const unsigned long long ra = stageB[p];
      const uint4 ha = GATH(ra);
      DOTS(ra, ha)
    }

    // Merge the 4 quarter-partials (lanes L, L^16, L^32, L^48 share dims).
#define QRED(v)                  \
    v += __shfl_xor(v, 16);      \
    v += __shfl_xor(v, 32);
    QRED(sr0) QRED(sr1) QRED(sr2) QRED(sr3)
    QRED(si0) QRED(si1) QRED(si2) QRED(si3)
#undef QRED

    const float dn = dvec[n];
    if (lane < 16) {
      uint2 rv, iv;
      rv.x = pack_bf16x2(dn * sr0, dn * sr1);
      rv.y = pack_bf16x2(dn * sr2, dn * sr3);
      iv.x = pack_bf16x2(dn * si0, dn * si1);
      iv.y = pack_bf16x2(dn * si2, dn * si3);
      *reinterpret_cast<uint2*>(&zs[l][4 * lane]) = rv;
      *reinterpret_cast<uint2*>(&zs[l][64 + 4 * lane]) = iv;
    }
  }
#undef DOTS
#undef GATH
#undef DOT2
  __syncthreads();

  // Epilogue: Out[node][f] = sum_k Zcat[node][k]*A_comb[k][f] + cvec[f].
  // 4 node-groups x 8 feature-tiles; wave w does feature tile w for all 4
  // node groups (verified r9/r11 mapping). Direct strided stores.
  {
    const int m = lane & 15;
    const int q = lane >> 4;
    const int ft = wave;
#pragma unroll
    for (int g = 0; g < 4; ++g) {
      bf16x8 a[4];
#pragma unroll
      for (int c = 0; c < 4; ++c)
        a[c] = *reinterpret_cast<const bf16x8*>(&zs[g * 16 + m][c * 32 + q * 8]);

      f32x4 acc = (f32x4){0.f, 0.f, 0.f, 0.f};
      const unsigned short* brow = At + (size_t)(ft * 16 + m) * 128 + q * 8;
#pragma unroll
      for (int c = 0; c < 4; ++c) {
        bf16x8 bfrag = *reinterpret_cast<const bf16x8*>(brow + c * 32);
        acc = __builtin_amdgcn_mfma_f32_16x16x32_bf16(a[c], bfrag, acc, 0, 0, 0);
      }

      const int nf = ft * 16 + m;
      const float bias = cvec[nf];
      float* outp = (nf < 64) ? zr_out : zi_out;
      const int nnn = nf & 63;
#pragma unroll
      for (int r = 0; r < 4; ++r) {
        const int node = nbase + g * 16 + q * 4 + r;
        if (node < N_NODES) outp[(size_t)node * 64 + nnn] = acc[r] + bias;
      }
    }
  }
}

extern "C" void kernel_launch(void* const* d_in, const int* in_sizes, int n_in,
                              void* d_out, int out_size, void* d_ws, size_t ws_size,
                              hipStream_t stream) {
  const float* h_real = (const float*)d_in[0];
  const float* h_imag = (const float*)d_in[1];
  const float* dvec   = (const float*)d_in[2];
  const float* w_real = (const float*)d_in[3];
  const float* w_imag = (const float*)d_in[4];
  const int*   src    = (const int*)d_in[5];
  const int*   dst    = (const int*)d_in[6];
  const float* W1     = (const float*)d_in[7];
  const float* b1     = (const float*)d_in[8];
  const float* W2     = (const float*)d_in[9];
  const float* b2     = (const float*)d_in[10];

  char* ws = (char*)d_ws;
  unsigned short* At = (unsigned short*)ws;                          // 32 KB
  float* cvec = (float*)(ws + 128 * 128 * 2);                        // 1 KB
  unsigned long long* records = (unsigned long long*)(ws + 33792);   // 12.8 MB
  unsigned* hpack = (unsigned*)(ws + 33792 + (size_t)N_EDGES * 8);   // 25.6 MB
  int* counts = (int*)(ws + 33792 + (size_t)N_EDGES * 8 + (size_t)N_NODES * DIM * 4);
  int* bsum = counts + NCOUNTS;
  int* bpre = bsum + NSB;

  float* zr_out = (float*)d_out;
  float* zi_out = zr_out + (size_t)N_NODES * DIM;

  setup_fused_kernel<<<PACKB4 + 64 + B1, 256, 0, stream>>>(
      h_real, h_imag, (unsigned*)hpack, W1, b1, W2, b2, At, cvec, dst, counts);
  scan1_kernel<<<NSB, SCAN_BLOCK, 0, stream>>>(counts, bsum);
  scan2_kernel<<<1, 256, 0, stream>>>(bsum, bpre);
  partition_kernel<<<B1, 512, 0, stream>>>(src, dst, dvec, w_real, w_imag,
                                           counts, bpre, records);
  pull_sorted_kernel<<<K1 * 4, 512, 0, stream>>>(
      records, counts, bpre, dvec, hpack, At, cvec, zr_out, zi_out);
}